// Round 3
// baseline (532.855 us; speedup 1.0000x reference)
//
#include <hip/hip_runtime.h>
#include <hip/hip_bf16.h>

// Attention with relative position bias: B=1, L=4096, D=512, H=8, HD=64
// bias[h,i,j] = rel[h, j-i+4095]

typedef __attribute__((ext_vector_type(8))) short bf16x8;
typedef __attribute__((ext_vector_type(4))) short bf16x4;
typedef __attribute__((ext_vector_type(4))) float f32x4;
typedef __attribute__((ext_vector_type(2))) unsigned u32x2;

__device__ __forceinline__ short f2bf(float f) {
    unsigned u = __builtin_bit_cast(unsigned, f);
    u += 0x7fff + ((u >> 16) & 1);
    return (short)(u >> 16);
}

__device__ __forceinline__ f32x4 mfma32(bf16x8 a, bf16x8 b, f32x4 c) {
    return __builtin_amdgcn_mfma_f32_16x16x32_bf16(a, b, c, 0, 0, 0);
}

__device__ __forceinline__ f32x4 mfma16(bf16x4 a, bf16x4 b, f32x4 c) {
#if __has_builtin(__builtin_amdgcn_mfma_f32_16x16x16bf16_1k)
    return __builtin_amdgcn_mfma_f32_16x16x16bf16_1k(a, b, c, 0, 0, 0);
#else
    asm volatile("v_mfma_f32_16x16x16_bf16 %0, %1, %2, %0\n\ts_nop 7\n\ts_nop 7"
                 : "+v"(c) : "v"(a), "v"(b));
    return c;
#endif
}

__device__ __forceinline__ unsigned cvtpk(float a, float b) {
    unsigned r;
    asm("v_cvt_pk_bf16_f32 %0, %1, %2" : "=v"(r) : "v"(a), "v"(b));
    return r;
}

__device__ __forceinline__ void gll16(const short* src, short* ldsdst) {
    __builtin_amdgcn_global_load_lds(
        (const __attribute__((address_space(1))) unsigned*)src,
        (__attribute__((address_space(3))) unsigned*)ldsdst, 16, 0, 0);
}

// ---------------- prep kernels ----------------
__global__ __launch_bounds__(256) void k_prep_xp(const float* __restrict__ x,
                                                 const float* __restrict__ pos,
                                                 short* __restrict__ xp) {
    int i = (blockIdx.x * 256 + threadIdx.x) * 8;
    float4 a0 = *(const float4*)(x + i);
    float4 a1 = *(const float4*)(x + i + 4);
    float4 b0 = *(const float4*)(pos + i);
    float4 b1 = *(const float4*)(pos + i + 4);
    bf16x8 v;
    v[0] = f2bf(a0.x + b0.x); v[1] = f2bf(a0.y + b0.y);
    v[2] = f2bf(a0.z + b0.z); v[3] = f2bf(a0.w + b0.w);
    v[4] = f2bf(a1.x + b1.x); v[5] = f2bf(a1.y + b1.y);
    v[6] = f2bf(a1.z + b1.z); v[7] = f2bf(a1.w + b1.w);
    *(bf16x8*)(xp + i) = v;
}

__global__ __launch_bounds__(256) void k_prep_wqkv(const float* __restrict__ Wq,
                                                   const float* __restrict__ Wk,
                                                   const float* __restrict__ Wv,
                                                   short* __restrict__ WT) {
    int idx = blockIdx.x * 256 + threadIdx.x;   // 1536*512
    int n = idx >> 9, k = idx & 511;
    int nn = n & 511;
    const float* src = (n < 512) ? Wq : (n < 1024 ? Wk : Wv);
    float scale = (n < 512) ? 0.125f : 1.0f;
    WT[idx] = f2bf(src[k * 512 + nn] * scale);
}

__global__ __launch_bounds__(256) void k_prep_wo(const float* __restrict__ Wo,
                                                 short* __restrict__ WoT) {
    int idx = blockIdx.x * 256 + threadIdx.x;   // 512*512
    int n = idx >> 9, k = idx & 511;
    WoT[idx] = f2bf(Wo[k * 512 + n]);
}

// V transpose: Vg [h][kv=4096][d=64] -> VT [h][d=64][kv=4096]
__global__ __launch_bounds__(256) void k_vt(const short* __restrict__ Vg,
                                            short* __restrict__ VT) {
    __shared__ short tile[64][72];
    const int tid = threadIdx.x;
    const int h = blockIdx.y, kvb = blockIdx.x * 64;
    const short* src = Vg + (size_t)h * 4096 * 64;
    short* dst = VT + (size_t)h * 64 * 4096;
    #pragma unroll
    for (int i = 0; i < 2; ++i) {
        int ch = tid + 256 * i;
        int r = ch >> 3, c = (ch & 7) * 8;
        *(uint4*)&tile[r][c] = *(const uint4*)(src + (size_t)(kvb + r) * 64 + c);
    }
    __syncthreads();
    #pragma unroll
    for (int i = 0; i < 2; ++i) {
        int ch = tid + 256 * i;
        int d = ch >> 3, kc = (ch & 7) * 8;
        bf16x8 v;
        #pragma unroll
        for (int j = 0; j < 8; ++j) v[j] = tile[kc + j][d];
        *(bf16x8*)(dst + (size_t)d * 4096 + kvb + kc) = v;
    }
}

// ---------------- GEMM: C[M x N] = A[M x 512] * Bt[N x 512]^T ----------------
template <int MODE>
__global__ __launch_bounds__(256) void k_gemm(const short* __restrict__ A,
                                              const short* __restrict__ Bt,
                                              const float* __restrict__ bias0,
                                              const float* __restrict__ bias1,
                                              const float* __restrict__ bias2,
                                              short* __restrict__ Qg,
                                              short* __restrict__ Kg,
                                              short* __restrict__ Vg,
                                              float* __restrict__ Cout) {
    __shared__ short Al[128][72];
    __shared__ short Bl[128][72];
    const int tid = threadIdx.x;
    const int lane = tid & 63, wid = tid >> 6;
    const int wm = wid >> 1, wn = wid & 1;
    const int mb = blockIdx.y * 128, nb = blockIdx.x * 128;
    const int lr = lane & 15, lg = lane >> 4;

    f32x4 acc[4][4] = {};

    for (int kk = 0; kk < 512; kk += 64) {
        #pragma unroll
        for (int i = 0; i < 4; ++i) {
            int o = tid + 256 * i;
            int row = o >> 3, c8 = (o & 7) * 8;
            *(uint4*)(&Al[row][c8]) = *(const uint4*)(A + (size_t)(mb + row) * 512 + kk + c8);
            *(uint4*)(&Bl[row][c8]) = *(const uint4*)(Bt + (size_t)(nb + row) * 512 + kk + c8);
        }
        __syncthreads();
        #pragma unroll
        for (int ks = 0; ks < 2; ++ks) {
            bf16x8 af[4], bfr[4];
            #pragma unroll
            for (int t = 0; t < 4; ++t) {
                af[t]  = *(const bf16x8*)(&Al[wm * 64 + t * 16 + lr][ks * 32 + lg * 8]);
                bfr[t] = *(const bf16x8*)(&Bl[wn * 64 + t * 16 + lr][ks * 32 + lg * 8]);
            }
            #pragma unroll
            for (int mt = 0; mt < 4; ++mt)
                #pragma unroll
                for (int nt = 0; nt < 4; ++nt)
                    acc[mt][nt] = mfma32(af[mt], bfr[nt], acc[mt][nt]);
        }
        __syncthreads();
    }

    #pragma unroll
    for (int mt = 0; mt < 4; ++mt) {
        #pragma unroll
        for (int nt = 0; nt < 4; ++nt) {
            #pragma unroll
            for (int r = 0; r < 4; ++r) {
                int m = mb + wm * 64 + mt * 16 + lg * 4 + r;
                int n = nb + wn * 64 + nt * 16 + lr;
                float v = acc[mt][nt][r];
                if (MODE == 0) {
                    int which = n >> 9;
                    int nn = n & 511;
                    int hh = nn >> 6, hd = nn & 63;
                    const float* bp = (which == 0) ? bias0 : (which == 1 ? bias1 : bias2);
                    v += bp[nn] * (which == 0 ? 0.125f : 1.0f);
                    short* dst = (which == 0) ? Qg : (which == 1 ? Kg : Vg);
                    dst[((size_t)hh * 4096 + m) * 64 + hd] = f2bf(v);
                } else {
                    Cout[(size_t)m * 512 + n] = v + bias0[n];
                }
            }
        }
    }
}

// ---------------- flash attention, swapped-QK^T, static max ----------------
// grid (32, 8); 8 waves: wave = (g = wq&1 [q-half], sp = wq>>1 [kv quarter])
// each wave: 64 q rows (qb + g*64 + qt*16 + lr), kv range [sp*1024, sp*1024+1024)
__global__ __launch_bounds__(512, 1) void k_attn2(const short* __restrict__ Qg,
                                                  const short* __restrict__ Kg,
                                                  const short* __restrict__ VT,
                                                  const float* __restrict__ rel,
                                                  short* __restrict__ AO) {
    __shared__ __align__(16) char smem[147968];
    short* KlB = (short*)smem;                 // [buf*4+sp][64 kv][8 ch] XOR-swizzled
    short* VsB = (short*)(smem + 65536);       // [buf*4+sp][64 d][8 ch]  XOR-swizzled
    float* biasl = (float*)(smem + 131072);    // 4224 floats

    const int tid = threadIdx.x;
    const int lane = tid & 63, wq = tid >> 6;
    const int lr = lane & 15, lg = lane >> 4;
    const int g = wq & 1, sp = wq >> 1;
    const int h = blockIdx.y;
    const int qb = blockIdx.x * 128;

    const short* Qh = Qg + (size_t)h * 4096 * 64;
    const short* Kh = Kg + (size_t)h * 4096 * 64;
    const short* VTh = VT + (size_t)h * 64 * 4096;
    const float* relh = rel + h * 8192;

    // per-lane pre-swizzled staging source offsets (elements)
    // K: row-major [kv][64 d]; LDS chunk (row,kc) <- global chunk (row, kc^(row&7))
    // V^T: [d][4096 kv]; LDS chunk (d,kc) <- global chunk (d, kc^(d&7)) of the tile
    int koffE[4], voffE[4];
    #pragma unroll
    for (int i = 0; i < 4; ++i) {
        int ch = g * 256 + i * 64 + lane;          // chunk in tile [0,512)
        int row = ch >> 3, kc = ch & 7;
        koffE[i] = row * 64 + (kc ^ (row & 7)) * 8;
        voffE[i] = row * 4096 + (kc ^ (row & 7)) * 8;
    }

    // Q fragments (B-operand layout): q = lr, d = dk*32 + lg*8 + e
    bf16x8 qf[4][2];
    #pragma unroll
    for (int qt = 0; qt < 4; ++qt)
        #pragma unroll
        for (int dk = 0; dk < 2; ++dk)
            qf[qt][dk] = *(const bf16x8*)(Qh + (size_t)(qb + g * 64 + qt * 16 + lr) * 64 + dk * 32 + lg * 8);

    // stage whole bias window once: biasl[j] = relh[3968 - qb + j], j in [0,4224)
    for (int j = tid; j < 4224; j += 512) biasl[j] = relh[3968 - qb + j];

    const int kvbase = sp * 1024;

    // prologue stage buf 0
    {
        const short* ks = Kh + (size_t)kvbase * 64;
        const short* vs = VTh + kvbase;
        short* kd = KlB + sp * 4096;
        short* vd = VsB + sp * 4096;
        #pragma unroll
        for (int i = 0; i < 4; ++i) {
            gll16(ks + koffE[i], kd + (g * 256 + i * 64) * 8);
            gll16(vs + voffE[i], vd + (g * 256 + i * 64) * 8);
        }
    }
    __syncthreads();

    f32x4 acc[4][4] = {};     // [qt][dt]; lane: q = lr, d = dt*16 + lg*4 + r
    float lsum[4] = {0.f, 0.f, 0.f, 0.f};
    const float L2E = 1.4426950408889634f;

    #pragma unroll 1
    for (int it = 0; it < 16; ++it) {
        const int buf = it & 1;
        if (it + 1 < 16) {   // prefetch next tile into other buffer
            const short* ks = Kh + (size_t)(kvbase + (it + 1) * 64) * 64;
            const short* vs = VTh + kvbase + (it + 1) * 64;
            short* kd = KlB + ((buf ^ 1) * 4 + sp) * 4096;
            short* vd = VsB + ((buf ^ 1) * 4 + sp) * 4096;
            #pragma unroll
            for (int i = 0; i < 4; ++i) {
                gll16(ks + koffE[i], kd + (g * 256 + i * 64) * 8);
                gll16(vs + voffE[i], vd + (g * 256 + i * 64) * 8);
            }
        }

        const short* Kt = KlB + (buf * 4 + sp) * 4096;
        const char*  Vtb = (const char*)(VsB + (buf * 4 + sp) * 4096);

        // bias regs (pre-multiplied by log2e)
        float bwL[7][4];
        {
            int jb = kvbase + it * 64 + 127 + lg * 4 - g * 64 - lr - 48;
            #pragma unroll
            for (int gi = 0; gi < 7; ++gi)
                #pragma unroll
                for (int r = 0; r < 4; ++r)
                    bwL[gi][r] = biasl[jb + gi * 16 + r] * L2E;
        }

        #pragma unroll
        for (int t = 0; t < 4; ++t) {
            // K frags (A-operand): kv = t*16+lr, d = dk*32+lg*8+e ; chunk-XOR swizzle
            bf16x8 kf0 = *(const bf16x8*)(Kt + (t * 16 + lr) * 64 + ((lg) ^ (lr & 7)) * 8);
            bf16x8 kf1 = *(const bf16x8*)(Kt + (t * 16 + lr) * 64 + ((4 + lg) ^ (lr & 7)) * 8);
            // V^T frags (A-operand of 16x16x16): d = dt*16+lr, kv = t*16 + lg*4 + e
            // byte addr = d*128 + ((t*2 + (lg>>1)) ^ (lr&7))*16 + (lg&1)*8
            bf16x4 vf[4];
            const int vsw = (((t * 2 + (lg >> 1)) ^ (lr & 7)) << 4) + (lg & 1) * 8;
            #pragma unroll
            for (int dt = 0; dt < 4; ++dt)
                vf[dt] = *(const bf16x4*)(Vtb + (dt * 16 + lr) * 128 + vsw);

            // S^T = K · Q^T : lane holds q = lr (col), kv = t*16 + lg*4 + r (row)
            f32x4 sv[4];
            #pragma unroll
            for (int qt = 0; qt < 4; ++qt) {
                f32x4 z = {0.f, 0.f, 0.f, 0.f};
                z = mfma32(kf0, qf[qt][0], z);
                z = mfma32(kf1, qf[qt][1], z);
                sv[qt] = z;
            }

            // bias + exp2 (static max) + pack to bf16
            bf16x4 pf[4];
            #pragma unroll
            for (int qt = 0; qt < 4; ++qt) {
                float p0 = exp2f(fmaf(sv[qt][0], L2E, bwL[t - qt + 3][0]));
                float p1 = exp2f(fmaf(sv[qt][1], L2E, bwL[t - qt + 3][1]));
                float p2 = exp2f(fmaf(sv[qt][2], L2E, bwL[t - qt + 3][2]));
                float p3 = exp2f(fmaf(sv[qt][3], L2E, bwL[t - qt + 3][3]));
                lsum[qt] += (p0 + p1) + (p2 + p3);
                u32x2 pk;
                pk[0] = cvtpk(p0, p1);
                pk[1] = cvtpk(p2, p3);
                pf[qt] = __builtin_bit_cast(bf16x4, pk);
            }

            // O^T += V^T · P : 16x16x16 mfma, k-slots match S^T rows exactly
            #pragma unroll
            for (int qt = 0; qt < 4; ++qt)
                #pragma unroll
                for (int dt = 0; dt < 4; ++dt)
                    acc[qt][dt] = mfma16(vf[dt], pf[qt], acc[qt][dt]);
        }
        __syncthreads();
    }

    // cross-lane l reduction (q=lr owned by lanes lr, lr+16, lr+32, lr+48)
    #pragma unroll
    for (int qt = 0; qt < 4; ++qt) {
        float v = lsum[qt];
        v += __shfl_xor(v, 16);
        v += __shfl_xor(v, 32);
        lsum[qt] = v;
    }

    // in-LDS merge of the 4 kv-splits (overlay K/V buffers; dead now)
    float* Opart = (float*)smem;               // [8][16][68]
    float* Lpart = (float*)(smem + 36864);     // 128 floats
    #pragma unroll 1
    for (int qt = 0; qt < 4; ++qt) {
        #pragma unroll
        for (int dt = 0; dt < 4; ++dt)
            *(f32x4*)&Opart[((size_t)(g * 4 + sp) * 16 + lr) * 68 + dt * 16 + lg * 4] = acc[qt][dt];
        if (lg == 0) Lpart[(g * 4 + sp) * 16 + lr] = lsum[qt];
        __syncthreads();
        {
            int g2 = tid >> 8, qi = (tid >> 4) & 15, d4 = (tid & 15) * 4;
            f32x4 s = {0.f, 0.f, 0.f, 0.f};
            float lt = 0.f;
            #pragma unroll
            for (int s2 = 0; s2 < 4; ++s2) {
                s += *(const f32x4*)&Opart[((size_t)(g2 * 4 + s2) * 16 + qi) * 68 + d4];
                lt += Lpart[(g2 * 4 + s2) * 16 + qi];
            }
            float inv = 1.0f / lt;
            bf16x4 o;
            o[0] = f2bf(s[0] * inv); o[1] = f2bf(s[1] * inv);
            o[2] = f2bf(s[2] * inv); o[3] = f2bf(s[3] * inv);
            int q = qb + g2 * 64 + qt * 16 + qi;
            *(bf16x4*)(AO + (size_t)q * 512 + h * 64 + d4) = o;
        }
        __syncthreads();
    }
}

// ---------------- launch ----------------
extern "C" void kernel_launch(void* const* d_in, const int* in_sizes, int n_in,
                              void* d_out, int out_size, void* d_ws, size_t ws_size,
                              hipStream_t stream) {
    const float* x   = (const float*)d_in[0];
    const float* pos = (const float*)d_in[1];
    const float* rel = (const float*)d_in[2];
    const float* Wq  = (const float*)d_in[3];
    const float* bq  = (const float*)d_in[4];
    const float* Wk  = (const float*)d_in[5];
    const float* bk  = (const float*)d_in[6];
    const float* Wv  = (const float*)d_in[7];
    const float* bv  = (const float*)d_in[8];
    const float* Wo  = (const float*)d_in[9];
    const float* bo  = (const float*)d_in[10];
    float* out = (float*)d_out;

    char* ws = (char*)d_ws;
    short* xp    = (short*)ws;  ws += (size_t)4096 * 512 * 2;   // reused as VT after gemm0
    short* WqkvT = (short*)ws;  ws += (size_t)1536 * 512 * 2;
    short* WoT   = (short*)ws;  ws += (size_t)512 * 512 * 2;
    short* Qg    = (short*)ws;  ws += (size_t)8 * 4096 * 64 * 2;
    short* Kg    = (short*)ws;  ws += (size_t)8 * 4096 * 64 * 2;
    short* Vg    = (short*)ws;  ws += (size_t)8 * 4096 * 64 * 2;
    short* AO    = (short*)ws;  ws += (size_t)4096 * 512 * 2;
    short* VT    = xp;          // xp is dead after k_gemm<0>

    k_prep_xp<<<dim3(4096 * 512 / (256 * 8)), 256, 0, stream>>>(x, pos, xp);
    k_prep_wqkv<<<dim3(1536 * 512 / 256), 256, 0, stream>>>(Wq, Wk, Wv, WqkvT);
    k_prep_wo<<<dim3(512 * 512 / 256), 256, 0, stream>>>(Wo, WoT);

    k_gemm<0><<<dim3(12, 32), 256, 0, stream>>>(xp, WqkvT, bq, bk, bv, Qg, Kg, Vg, nullptr);
    k_vt<<<dim3(64, 8), 256, 0, stream>>>(Vg, VT);
    k_attn2<<<dim3(32, 8), 512, 0, stream>>>(Qg, Kg, VT, rel, AO);
    k_gemm<1><<<dim3(4, 32), 256, 0, stream>>>(AO, WoT, bo, nullptr, nullptr,
                                               nullptr, nullptr, nullptr, out);
}

// Round 6
// 135.907 us; speedup vs baseline: 3.9207x; 3.9207x over previous
//
#include <hip/hip_runtime.h>
#include <hip/hip_bf16.h>

// Attention with relative position bias: B=1, L=4096, D=512, H=8, HD=64
// bias[h,i,j] = rel[h, j-i+4095]

typedef __attribute__((ext_vector_type(8))) short bf16x8;
typedef __attribute__((ext_vector_type(4))) short bf16x4;
typedef __attribute__((ext_vector_type(4))) float f32x4;
typedef __attribute__((ext_vector_type(2))) unsigned u32x2;

__device__ __forceinline__ short f2bf(float f) {
    unsigned u = __builtin_bit_cast(unsigned, f);
    u += 0x7fff + ((u >> 16) & 1);
    return (short)(u >> 16);
}

__device__ __forceinline__ float bf2f(short s) {
    unsigned u = ((unsigned)(unsigned short)s) << 16;
    return __builtin_bit_cast(float, u);
}

__device__ __forceinline__ f32x4 mfma32(bf16x8 a, bf16x8 b, f32x4 c) {
    return __builtin_amdgcn_mfma_f32_16x16x32_bf16(a, b, c, 0, 0, 0);
}

__device__ __forceinline__ unsigned cvtpk(float a, float b) {
    unsigned r;
    asm("v_cvt_pk_bf16_f32 %0, %1, %2" : "=v"(r) : "v"(a), "v"(b));
    return r;
}

__device__ __forceinline__ void gll16(const short* src, short* ldsdst) {
    __builtin_amdgcn_global_load_lds(
        (const __attribute__((address_space(1))) unsigned*)src,
        (__attribute__((address_space(3))) unsigned*)ldsdst, 16, 0, 0);
}

// ---------------- prep kernels ----------------
__global__ __launch_bounds__(256) void k_prep_xp(const float* __restrict__ x,
                                                 const float* __restrict__ pos,
                                                 short* __restrict__ xp) {
    int i = (blockIdx.x * 256 + threadIdx.x) * 8;
    float4 a0 = *(const float4*)(x + i);
    float4 a1 = *(const float4*)(x + i + 4);
    float4 b0 = *(const float4*)(pos + i);
    float4 b1 = *(const float4*)(pos + i + 4);
    bf16x8 v;
    v[0] = f2bf(a0.x + b0.x); v[1] = f2bf(a0.y + b0.y);
    v[2] = f2bf(a0.z + b0.z); v[3] = f2bf(a0.w + b0.w);
    v[4] = f2bf(a1.x + b1.x); v[5] = f2bf(a1.y + b1.y);
    v[6] = f2bf(a1.z + b1.z); v[7] = f2bf(a1.w + b1.w);
    *(bf16x8*)(xp + i) = v;
}

__global__ __launch_bounds__(256) void k_prep_wqkv(const float* __restrict__ Wq,
                                                   const float* __restrict__ Wk,
                                                   const float* __restrict__ Wv,
                                                   short* __restrict__ WT) {
    int idx = blockIdx.x * 256 + threadIdx.x;   // 1536*512
    int n = idx >> 9, k = idx & 511;
    int nn = n & 511;
    const float* src = (n < 512) ? Wq : (n < 1024 ? Wk : Wv);
    float scale = (n < 512) ? 0.125f : 1.0f;
    WT[idx] = f2bf(src[k * 512 + nn] * scale);
}

__global__ __launch_bounds__(256) void k_prep_wo(const float* __restrict__ Wo,
                                                 short* __restrict__ WoT) {
    int idx = blockIdx.x * 256 + threadIdx.x;   // 512*512
    int n = idx >> 9, k = idx & 511;
    WoT[idx] = f2bf(Wo[k * 512 + n]);
}

// V transpose: Vg [h][kv=4096][d=64] -> VT [h][d=64][kv=4096]
__global__ __launch_bounds__(256) void k_vt(const short* __restrict__ Vg,
                                            short* __restrict__ VT) {
    __shared__ short tile[64][72];
    const int tid = threadIdx.x;
    const int h = blockIdx.y, kvb = blockIdx.x * 64;
    const short* src = Vg + (size_t)h * 4096 * 64;
    short* dst = VT + (size_t)h * 64 * 4096;
    #pragma unroll
    for (int i = 0; i < 2; ++i) {
        int ch = tid + 256 * i;
        int r = ch >> 3, c = (ch & 7) * 8;
        *(uint4*)&tile[r][c] = *(const uint4*)(src + (size_t)(kvb + r) * 64 + c);
    }
    __syncthreads();
    #pragma unroll
    for (int i = 0; i < 2; ++i) {
        int ch = tid + 256 * i;
        int d = ch >> 3, kc = (ch & 7) * 8;
        bf16x8 v;
        #pragma unroll
        for (int j = 0; j < 8; ++j) v[j] = tile[kc + j][d];
        *(bf16x8*)(dst + (size_t)d * 4096 + kvb + kc) = v;
    }
}

// ---------------- GEMM: C[M x N] = A[M x 512] * Bt[N x 512]^T ----------------
template <int MODE>
__global__ __launch_bounds__(256) void k_gemm(const short* __restrict__ A,
                                              const short* __restrict__ Bt,
                                              const float* __restrict__ bias0,
                                              const float* __restrict__ bias1,
                                              const float* __restrict__ bias2,
                                              short* __restrict__ Qg,
                                              short* __restrict__ Kg,
                                              short* __restrict__ Vg,
                                              float* __restrict__ Cout) {
    __shared__ short Al[128][72];
    __shared__ short Bl[128][72];
    const int tid = threadIdx.x;
    const int lane = tid & 63, wid = tid >> 6;
    const int wm = wid >> 1, wn = wid & 1;
    const int mb = blockIdx.y * 128, nb = blockIdx.x * 128;
    const int lr = lane & 15, lg = lane >> 4;

    f32x4 acc[4][4] = {};

    for (int kk = 0; kk < 512; kk += 64) {
        #pragma unroll
        for (int i = 0; i < 4; ++i) {
            int o = tid + 256 * i;
            int row = o >> 3, c8 = (o & 7) * 8;
            *(uint4*)(&Al[row][c8]) = *(const uint4*)(A + (size_t)(mb + row) * 512 + kk + c8);
            *(uint4*)(&Bl[row][c8]) = *(const uint4*)(Bt + (size_t)(nb + row) * 512 + kk + c8);
        }
        __syncthreads();
        #pragma unroll
        for (int ks = 0; ks < 2; ++ks) {
            bf16x8 af[4], bfr[4];
            #pragma unroll
            for (int t = 0; t < 4; ++t) {
                af[t]  = *(const bf16x8*)(&Al[wm * 64 + t * 16 + lr][ks * 32 + lg * 8]);
                bfr[t] = *(const bf16x8*)(&Bl[wn * 64 + t * 16 + lr][ks * 32 + lg * 8]);
            }
            #pragma unroll
            for (int mt = 0; mt < 4; ++mt)
                #pragma unroll
                for (int nt = 0; nt < 4; ++nt)
                    acc[mt][nt] = mfma32(af[mt], bfr[nt], acc[mt][nt]);
        }
        __syncthreads();
    }

    #pragma unroll
    for (int mt = 0; mt < 4; ++mt) {
        #pragma unroll
        for (int nt = 0; nt < 4; ++nt) {
            #pragma unroll
            for (int r = 0; r < 4; ++r) {
                int m = mb + wm * 64 + mt * 16 + lg * 4 + r;
                int n = nb + wn * 64 + nt * 16 + lr;
                float v = acc[mt][nt][r];
                if (MODE == 0) {
                    int which = n >> 9;
                    int nn = n & 511;
                    int hh = nn >> 6, hd = nn & 63;
                    const float* bp = (which == 0) ? bias0 : (which == 1 ? bias1 : bias2);
                    v += bp[nn] * (which == 0 ? 0.125f : 1.0f);
                    short* dst = (which == 0) ? Qg : (which == 1 ? Kg : Vg);
                    dst[((size_t)hh * 4096 + m) * 64 + hd] = f2bf(v);
                } else {
                    Cout[(size_t)m * 512 + n] = v + bias0[n];
                }
            }
        }
    }
}

// ---------------- flash attention, swapped-QK^T, static max ----------------
// grid (32, 8); 8 waves: wave = (g = wq&1 [q-half], sp = wq>>1 [kv quarter])
// each wave: 64 q rows (qb + g*64 + qt*16 + lr), kv range [sp*1024, sp*1024+1024)
// PV uses mfma_16x16x32 with P routed through a per-wave LDS buffer.
__global__ __launch_bounds__(512, 1) void k_attn2(const short* __restrict__ Qg,
                                                  const short* __restrict__ Kg,
                                                  const short* __restrict__ VT,
                                                  const float* __restrict__ rel,
                                                  short* __restrict__ AO) {
    __shared__ __align__(16) char smem[157952];
    short* KlB = (short*)smem;                 // [buf*4+sp][64 kv][8 ch] XOR-swizzled (64 KB)
    short* VsB = (short*)(smem + 65536);       // [buf*4+sp][64 d][8 ch]  XOR-swizzled (64 KB)
    // per-wave P buffer: [16 q][72 kv] bf16 (2304 B each, 18432 B total)
    // bias window as bf16: 4224 shorts (8448 B)
    short* biaslh = (short*)(smem + 149504);

    const int tid = threadIdx.x;
    const int lane = tid & 63, wq = tid >> 6;
    const int lr = lane & 15, lg = lane >> 4;
    const int g = wq & 1, sp = wq >> 1;
    const int h = blockIdx.y;
    const int qb = blockIdx.x * 128;

    short* Pw = (short*)(smem + 131072 + wq * 2304);

    const short* Qh = Qg + (size_t)h * 4096 * 64;
    const short* Kh = Kg + (size_t)h * 4096 * 64;
    const short* VTh = VT + (size_t)h * 64 * 4096;
    const float* relh = rel + h * 8192;

    // per-lane pre-swizzled staging source offsets (elements)
    int koffE[4], voffE[4];
    #pragma unroll
    for (int i = 0; i < 4; ++i) {
        int ch = g * 256 + i * 64 + lane;          // chunk in tile [0,512)
        int row = ch >> 3, kc = ch & 7;
        koffE[i] = row * 64 + (kc ^ (row & 7)) * 8;
        voffE[i] = row * 4096 + (kc ^ (row & 7)) * 8;
    }

    // Q fragments (B-operand layout): q = lr, d = dk*32 + lg*8 + e
    bf16x8 qf[4][2];
    #pragma unroll
    for (int qt = 0; qt < 4; ++qt)
        #pragma unroll
        for (int dk = 0; dk < 2; ++dk)
            qf[qt][dk] = *(const bf16x8*)(Qh + (size_t)(qb + g * 64 + qt * 16 + lr) * 64 + dk * 32 + lg * 8);

    // stage bias window (bf16): biaslh[j] = relh[3968 - qb + j], j in [0,4224)
    for (int j = tid; j < 4224; j += 512) biaslh[j] = f2bf(relh[3968 - qb + j]);

    const int kvbase = sp * 1024;

    // prologue stage buf 0
    {
        const short* ks = Kh + (size_t)kvbase * 64;
        const short* vs = VTh + kvbase;
        short* kd = KlB + sp * 4096;
        short* vd = VsB + sp * 4096;
        #pragma unroll
        for (int i = 0; i < 4; ++i) {
            gll16(ks + koffE[i], kd + (g * 256 + i * 64) * 8);
            gll16(vs + voffE[i], vd + (g * 256 + i * 64) * 8);
        }
    }
    __syncthreads();

    f32x4 acc[4][4] = {};     // [qt][dt]; lane: q = lr, d = dt*16 + lg*4 + r
    float lsum[4] = {0.f, 0.f, 0.f, 0.f};
    const float L2E = 1.4426950408889634f;

    #pragma unroll 1
    for (int it = 0; it < 16; ++it) {
        const int buf = it & 1;
        if (it + 1 < 16) {   // prefetch next tile into other buffer
            const short* ks = Kh + (size_t)(kvbase + (it + 1) * 64) * 64;
            const short* vs = VTh + kvbase + (it + 1) * 64;
            short* kd = KlB + ((buf ^ 1) * 4 + sp) * 4096;
            short* vd = VsB + ((buf ^ 1) * 4 + sp) * 4096;
            #pragma unroll
            for (int i = 0; i < 4; ++i) {
                gll16(ks + koffE[i], kd + (g * 256 + i * 64) * 8);
                gll16(vs + voffE[i], vd + (g * 256 + i * 64) * 8);
            }
        }

        const short* Kt = KlB + (buf * 4 + sp) * 4096;
        const char*  Vtb = (const char*)(VsB + (buf * 4 + sp) * 4096);

        // bias regs (pre-multiplied by log2e), bf16 source
        float bwL[7][4];
        {
            int jb = kvbase + it * 64 + 127 + lg * 4 - g * 64 - lr - 48;
            #pragma unroll
            for (int gi = 0; gi < 7; ++gi)
                #pragma unroll
                for (int r = 0; r < 4; ++r)
                    bwL[gi][r] = bf2f(biaslh[jb + gi * 16 + r]) * L2E;
        }

        // K frags once per iter: kv = t*16+lr, d = dk*32+lg*8+e ; chunk-XOR swizzle
        bf16x8 kf[4][2];
        #pragma unroll
        for (int t = 0; t < 4; ++t) {
            kf[t][0] = *(const bf16x8*)(Kt + (t * 16 + lr) * 64 + ((lg) ^ (lr & 7)) * 8);
            kf[t][1] = *(const bf16x8*)(Kt + (t * 16 + lr) * 64 + ((4 + lg) ^ (lr & 7)) * 8);
        }
        // V^T A-frags once per iter: d = dt*16+lr, kv = w*32 + lg*8 + e
        bf16x8 vf[4][2];
        #pragma unroll
        for (int dt = 0; dt < 4; ++dt)
            #pragma unroll
            for (int w = 0; w < 2; ++w)
                vf[dt][w] = *(const bf16x8*)(Vtb + (dt * 16 + lr) * 128 + (((w * 4 + lg) ^ (lr & 7)) << 4));

        #pragma unroll
        for (int qt = 0; qt < 4; ++qt) {
            // S^T = K · Q^T : lane holds q = lr (col), kv = t*16 + lg*4 + r (row)
            f32x4 sv[4];
            #pragma unroll
            for (int t = 0; t < 4; ++t) {
                f32x4 z = {0.f, 0.f, 0.f, 0.f};
                z = mfma32(kf[t][0], qf[qt][0], z);
                z = mfma32(kf[t][1], qf[qt][1], z);
                sv[t] = z;
            }

            // WAR fence: previous qt's P-reads must complete before overwriting Pw
            asm volatile("s_waitcnt lgkmcnt(0)" ::: "memory");
            __builtin_amdgcn_sched_barrier(0);

            // bias + exp2 (static max) + pack to bf16 -> per-wave LDS P buffer
            #pragma unroll
            for (int t = 0; t < 4; ++t) {
                float p0 = exp2f(fmaf(sv[t][0], L2E, bwL[t - qt + 3][0]));
                float p1 = exp2f(fmaf(sv[t][1], L2E, bwL[t - qt + 3][1]));
                float p2 = exp2f(fmaf(sv[t][2], L2E, bwL[t - qt + 3][2]));
                float p3 = exp2f(fmaf(sv[t][3], L2E, bwL[t - qt + 3][3]));
                lsum[qt] += (p0 + p1) + (p2 + p3);
                u32x2 pk;
                pk[0] = cvtpk(p0, p1);
                pk[1] = cvtpk(p2, p3);
                *(u32x2*)(Pw + lr * 72 + t * 16 + lg * 4) = pk;   // P[q=lr][kv]
            }
            __builtin_amdgcn_sched_barrier(0);

            // B-frags: P[kv = w*32 + lg*8 + e][q = lr] from Pw[lr][w*32+lg*8]
            bf16x8 pb0 = *(const bf16x8*)(Pw + lr * 72 + lg * 8);
            bf16x8 pb1 = *(const bf16x8*)(Pw + lr * 72 + 32 + lg * 8);

            // O^T += V^T · P  (16x16x32)
            #pragma unroll
            for (int dt = 0; dt < 4; ++dt) {
                acc[qt][dt] = mfma32(vf[dt][0], pb0, acc[qt][dt]);
                acc[qt][dt] = mfma32(vf[dt][1], pb1, acc[qt][dt]);
            }
        }
        __syncthreads();
    }

    // cross-lane l reduction (q=lr owned by lanes lr, lr+16, lr+32, lr+48)
    #pragma unroll
    for (int qt = 0; qt < 4; ++qt) {
        float v = lsum[qt];
        v += __shfl_xor(v, 16);
        v += __shfl_xor(v, 32);
        lsum[qt] = v;
    }

    // ---- single-pass split-merge epilogue ----
    // Every LDS address written exactly once (layout includes qt), one barrier.
    // Opart[(g*4+sp)][qt][lr][68] floats; Lpart[(g*4+sp)][qt][lr]
    float* Opart = (float*)smem;               // 139264 B (overlays dead K/V/P buffers)
    float* Lpart = (float*)(smem + 139264);    // 2048 B
    #pragma unroll
    for (int qt = 0; qt < 4; ++qt) {
        #pragma unroll
        for (int dt = 0; dt < 4; ++dt)
            *(f32x4*)&Opart[(((g * 4 + sp) * 4 + qt) * 16 + lr) * 68 + dt * 16 + lg * 4] = acc[qt][dt];
        if (lg == 0) Lpart[((g * 4 + sp) * 4 + qt) * 16 + lr] = lsum[qt];
    }
    __builtin_amdgcn_sched_barrier(0);
    __syncthreads();
    __builtin_amdgcn_sched_barrier(0);
    {
        const int g2 = tid >> 8, qi = (tid >> 4) & 15, d4 = (tid & 15) * 4;
        #pragma unroll
        for (int qt = 0; qt < 4; ++qt) {
            f32x4 s = {0.f, 0.f, 0.f, 0.f};
            float lt = 0.f;
            #pragma unroll
            for (int s2 = 0; s2 < 4; ++s2) {
                s += *(const f32x4*)&Opart[(((g2 * 4 + s2) * 4 + qt) * 16 + qi) * 68 + d4];
                lt += Lpart[((g2 * 4 + s2) * 4 + qt) * 16 + qi];
            }
            float inv = 1.0f / lt;
            bf16x4 o;
            o[0] = f2bf(s[0] * inv); o[1] = f2bf(s[1] * inv);
            o[2] = f2bf(s[2] * inv); o[3] = f2bf(s[3] * inv);
            int q = qb + g2 * 64 + qt * 16 + qi;
            *(bf16x4*)(AO + (size_t)q * 512 + h * 64 + d4) = o;
        }
    }
}

// ---------------- launch ----------------
extern "C" void kernel_launch(void* const* d_in, const int* in_sizes, int n_in,
                              void* d_out, int out_size, void* d_ws, size_t ws_size,
                              hipStream_t stream) {
    const float* x   = (const float*)d_in[0];
    const float* pos = (const float*)d_in[1];
    const float* rel = (const float*)d_in[2];
    const float* Wq  = (const float*)d_in[3];
    const float* bq  = (const float*)d_in[4];
    const float* Wk  = (const float*)d_in[5];
    const float* bk  = (const float*)d_in[6];
    const float* Wv  = (const float*)d_in[7];
    const float* bv  = (const float*)d_in[8];
    const float* Wo  = (const float*)d_in[9];
    const float* bo  = (const float*)d_in[10];
    float* out = (float*)d_out;

    char* ws = (char*)d_ws;
    short* xp    = (short*)ws;  ws += (size_t)4096 * 512 * 2;   // reused as VT after gemm0
    short* WqkvT = (short*)ws;  ws += (size_t)1536 * 512 * 2;
    short* WoT   = (short*)ws;  ws += (size_t)512 * 512 * 2;
    short* Qg    = (short*)ws;  ws += (size_t)8 * 4096 * 64 * 2;
    short* Kg    = (short*)ws;  ws += (size_t)8 * 4096 * 64 * 2;
    short* Vg    = (short*)ws;  ws += (size_t)8 * 4096 * 64 * 2;
    short* AO    = (short*)ws;  ws += (size_t)4096 * 512 * 2;
    short* VT    = xp;          // xp is dead after k_gemm<0>

    k_prep_xp<<<dim3(4096 * 512 / (256 * 8)), 256, 0, stream>>>(x, pos, xp);
    k_prep_wqkv<<<dim3(1536 * 512 / 256), 256, 0, stream>>>(Wq, Wk, Wv, WqkvT);
    k_prep_wo<<<dim3(512 * 512 / 256), 256, 0, stream>>>(Wo, WoT);

    k_gemm<0><<<dim3(12, 32), 256, 0, stream>>>(xp, WqkvT, bq, bk, bv, Qg, Kg, Vg, nullptr);
    k_vt<<<dim3(64, 8), 256, 0, stream>>>(Vg, VT);
    k_attn2<<<dim3(32, 8), 512, 0, stream>>>(Qg, Kg, VT, rel, AO);
    k_gemm<1><<<dim3(4, 32), 256, 0, stream>>>(AO, WoT, bo, nullptr, nullptr,
                                               nullptr, nullptr, nullptr, out);
}

// Round 7
// 130.006 us; speedup vs baseline: 4.0987x; 1.0454x over previous
//
#include <hip/hip_runtime.h>
#include <hip/hip_bf16.h>

// Attention with relative position bias: B=1, L=4096, D=512, H=8, HD=64
// bias[h,i,j] = rel[h, j-i+4095]

typedef __attribute__((ext_vector_type(8))) short bf16x8;
typedef __attribute__((ext_vector_type(4))) short bf16x4;
typedef __attribute__((ext_vector_type(4))) float f32x4;
typedef __attribute__((ext_vector_type(2))) unsigned u32x2;

#define QSCALE (0.125f * 1.4426950408889634f)   // 1/sqrt(64) * log2(e)

__device__ __forceinline__ short f2bf(float f) {
    unsigned u = __builtin_bit_cast(unsigned, f);
    u += 0x7fff + ((u >> 16) & 1);
    return (short)(u >> 16);
}

__device__ __forceinline__ f32x4 mfma32(bf16x8 a, bf16x8 b, f32x4 c) {
    return __builtin_amdgcn_mfma_f32_16x16x32_bf16(a, b, c, 0, 0, 0);
}

__device__ __forceinline__ unsigned cvtpk(float a, float b) {
    unsigned r;
    asm("v_cvt_pk_bf16_f32 %0, %1, %2" : "=v"(r) : "v"(a), "v"(b));
    return r;
}

// ---------------- prep kernels ----------------
__global__ __launch_bounds__(256) void k_prep_xp(const float* __restrict__ x,
                                                 const float* __restrict__ pos,
                                                 short* __restrict__ xp) {
    int i = (blockIdx.x * 256 + threadIdx.x) * 8;
    float4 a0 = *(const float4*)(x + i);
    float4 a1 = *(const float4*)(x + i + 4);
    float4 b0 = *(const float4*)(pos + i);
    float4 b1 = *(const float4*)(pos + i + 4);
    bf16x8 v;
    v[0] = f2bf(a0.x + b0.x); v[1] = f2bf(a0.y + b0.y);
    v[2] = f2bf(a0.z + b0.z); v[3] = f2bf(a0.w + b0.w);
    v[4] = f2bf(a1.x + b1.x); v[5] = f2bf(a1.y + b1.y);
    v[6] = f2bf(a1.z + b1.z); v[7] = f2bf(a1.w + b1.w);
    *(bf16x8*)(xp + i) = v;
}

__global__ __launch_bounds__(256) void k_prep_wqkv(const float* __restrict__ Wq,
                                                   const float* __restrict__ Wk,
                                                   const float* __restrict__ Wv,
                                                   short* __restrict__ WT) {
    int idx = blockIdx.x * 256 + threadIdx.x;   // 1536*512
    int n = idx >> 9, k = idx & 511;
    int nn = n & 511;
    const float* src = (n < 512) ? Wq : (n < 1024 ? Wk : Wv);
    float scale = (n < 512) ? QSCALE : 1.0f;
    WT[idx] = f2bf(src[k * 512 + nn] * scale);
}

__global__ __launch_bounds__(256) void k_prep_wo(const float* __restrict__ Wo,
                                                 short* __restrict__ WoT) {
    int idx = blockIdx.x * 256 + threadIdx.x;   // 512*512
    int n = idx >> 9, k = idx & 511;
    WoT[idx] = f2bf(Wo[k * 512 + n]);
}

// rel2 = rel * log2(e)   (f32, [8][8192])
__global__ __launch_bounds__(256) void k_prep_rel2(const float* __restrict__ rel,
                                                   float* __restrict__ rel2) {
    int i = blockIdx.x * 256 + threadIdx.x;
    rel2[i] = rel[i] * 1.4426950408889634f;
}

// V transpose: Vg [h][kv=4096][d=64] -> VT [h][d=64][kv=4096]
__global__ __launch_bounds__(256) void k_vt(const short* __restrict__ Vg,
                                            short* __restrict__ VT) {
    __shared__ short tile[64][72];
    const int tid = threadIdx.x;
    const int h = blockIdx.y, kvb = blockIdx.x * 64;
    const short* src = Vg + (size_t)h * 4096 * 64;
    short* dst = VT + (size_t)h * 64 * 4096;
    #pragma unroll
    for (int i = 0; i < 2; ++i) {
        int ch = tid + 256 * i;
        int r = ch >> 3, c = (ch & 7) * 8;
        *(uint4*)&tile[r][c] = *(const uint4*)(src + (size_t)(kvb + r) * 64 + c);
    }
    __syncthreads();
    #pragma unroll
    for (int i = 0; i < 2; ++i) {
        int ch = tid + 256 * i;
        int d = ch >> 3, kc = (ch & 7) * 8;
        bf16x8 v;
        #pragma unroll
        for (int j = 0; j < 8; ++j) v[j] = tile[kc + j][d];
        *(bf16x8*)(dst + (size_t)d * 4096 + kvb + kc) = v;
    }
}

// ---------------- GEMM: C[M x N] = A[M x 512] * Bt[N x 512]^T ----------------
template <int MODE>
__global__ __launch_bounds__(256) void k_gemm(const short* __restrict__ A,
                                              const short* __restrict__ Bt,
                                              const float* __restrict__ bias0,
                                              const float* __restrict__ bias1,
                                              const float* __restrict__ bias2,
                                              short* __restrict__ Qg,
                                              short* __restrict__ Kg,
                                              short* __restrict__ Vg,
                                              float* __restrict__ Cout) {
    __shared__ short Al[128][72];
    __shared__ short Bl[128][72];
    const int tid = threadIdx.x;
    const int lane = tid & 63, wid = tid >> 6;
    const int wm = wid >> 1, wn = wid & 1;
    const int mb = blockIdx.y * 128, nb = blockIdx.x * 128;
    const int lr = lane & 15, lg = lane >> 4;

    f32x4 acc[4][4] = {};

    for (int kk = 0; kk < 512; kk += 64) {
        #pragma unroll
        for (int i = 0; i < 4; ++i) {
            int o = tid + 256 * i;
            int row = o >> 3, c8 = (o & 7) * 8;
            *(uint4*)(&Al[row][c8]) = *(const uint4*)(A + (size_t)(mb + row) * 512 + kk + c8);
            *(uint4*)(&Bl[row][c8]) = *(const uint4*)(Bt + (size_t)(nb + row) * 512 + kk + c8);
        }
        __syncthreads();
        #pragma unroll
        for (int ks = 0; ks < 2; ++ks) {
            bf16x8 af[4], bfr[4];
            #pragma unroll
            for (int t = 0; t < 4; ++t) {
                af[t]  = *(const bf16x8*)(&Al[wm * 64 + t * 16 + lr][ks * 32 + lg * 8]);
                bfr[t] = *(const bf16x8*)(&Bl[wn * 64 + t * 16 + lr][ks * 32 + lg * 8]);
            }
            #pragma unroll
            for (int mt = 0; mt < 4; ++mt)
                #pragma unroll
                for (int nt = 0; nt < 4; ++nt)
                    acc[mt][nt] = mfma32(af[mt], bfr[nt], acc[mt][nt]);
        }
        __syncthreads();
    }

    #pragma unroll
    for (int mt = 0; mt < 4; ++mt) {
        #pragma unroll
        for (int nt = 0; nt < 4; ++nt) {
            #pragma unroll
            for (int r = 0; r < 4; ++r) {
                int m = mb + wm * 64 + mt * 16 + lg * 4 + r;
                int n = nb + wn * 64 + nt * 16 + lr;
                float v = acc[mt][nt][r];
                if (MODE == 0) {
                    int which = n >> 9;
                    int nn = n & 511;
                    int hh = nn >> 6, hd = nn & 63;
                    const float* bp = (which == 0) ? bias0 : (which == 1 ? bias1 : bias2);
                    v += bp[nn] * (which == 0 ? QSCALE : 1.0f);
                    short* dst = (which == 0) ? Qg : (which == 1 ? Kg : Vg);
                    dst[((size_t)hh * 4096 + m) * 64 + hd] = f2bf(v);
                } else {
                    Cout[(size_t)m * 512 + n] = v + bias0[n];
                }
            }
        }
    }
}

// ---------------- flash attention v3: no K/V LDS, barrier-free loop ----------
// grid 512 (1-D): head = bid & 7 (XCD-pinned), q-tile = (bid>>3)*64
// 4 waves; wave sp owns kv quarter [sp*1024, sp*1024+1024), all 64 q rows.
// K/V^T fragments read directly from global (L2-resident per XCD).
// Bias (pre-scaled by log2e) enters as the MFMA C operand.
// P goes through a per-wave LDS buffer (r6-proven pattern).
__global__ __launch_bounds__(256, 2) void k_attn3(const short* __restrict__ Qg,
                                                  const short* __restrict__ Kg,
                                                  const short* __restrict__ VT,
                                                  const float* __restrict__ rel2,
                                                  short* __restrict__ AO) {
    __shared__ __align__(16) char smem[70656];
    // loop phase: per-wave P buffer [16 q][72 kv] shorts at sp*2304 B
    // epilogue:   Opart [4 sp][4 qt][16 q][68] f32 (69632 B) + Lpart (1024 B)

    const int tid = threadIdx.x;
    const int lane = tid & 63, sp = tid >> 6;
    const int lr = lane & 15, lg = lane >> 4;
    const int bid = blockIdx.x;
    const int h = bid & 7;
    const int qb = (bid >> 3) * 64;

    short* Pw = (short*)smem + sp * 1152;

    const short* Qh = Qg + (size_t)h * 4096 * 64;
    const short* Kh = Kg + (size_t)h * 4096 * 64;
    const short* VTh = VT + (size_t)h * 64 * 4096;

    // Q fragments (B-operand): q = lr, d = dk*32 + lg*8 + e
    bf16x8 qf[4][2];
    #pragma unroll
    for (int qt = 0; qt < 4; ++qt)
        #pragma unroll
        for (int dk = 0; dk < 2; ++dk)
            qf[qt][dk] = *(const bf16x8*)(Qh + (size_t)(qb + qt * 16 + lr) * 64 + dk * 32 + lg * 8);

    const int kvbase = sp * 1024;
    const short* kp = Kh + (size_t)kvbase * 64;                       // +4096/iter
    const short* vp = VTh + kvbase;                                   // +64/iter
    const float* bp = rel2 + h * 8192 + (kvbase + 4095 - qb) + lg * 4 - lr;  // +64/iter

    f32x4 acc[4][4] = {};   // [qt][dt]; lane: q = lr, d = dt*16 + lg*4 + r
    f32x4 lacc[4] = {};     // ones-row colsums (all 4 regs identical)

    bf16x8 ones;
    #pragma unroll
    for (int i = 0; i < 8; ++i) ones[i] = (short)0x3F80;   // bf16 1.0

    #pragma unroll 1
    for (int it = 0; it < 16; ++it) {
        // K frags (A-operand): kv = t*16+lr, d = dk*32+lg*8+e  [global, L2]
        bf16x8 kf[4][2];
        #pragma unroll
        for (int t = 0; t < 4; ++t) {
            kf[t][0] = *(const bf16x8*)(kp + (size_t)(t * 16 + lr) * 64 + lg * 8);
            kf[t][1] = *(const bf16x8*)(kp + (size_t)(t * 16 + lr) * 64 + 32 + lg * 8);
        }
        // V^T frags (A-operand): d = dt*16+lr, kv = w*32+lg*8+e  [global, L2]
        bf16x8 vf[4][2];
        #pragma unroll
        for (int dt = 0; dt < 4; ++dt)
            #pragma unroll
            for (int w = 0; w < 2; ++w)
                vf[dt][w] = *(const bf16x8*)(vp + (size_t)(dt * 16 + lr) * 4096 + w * 32 + lg * 8);

        #pragma unroll
        for (int qt = 0; qt < 4; ++qt) {
            // bias C-init: cin[t][r] = rel2[kv - q + 4095] (already *log2e)
            f32x4 cin[4];
            #pragma unroll
            for (int t = 0; t < 4; ++t)
                #pragma unroll
                for (int r = 0; r < 4; ++r)
                    cin[t][r] = bp[(t - qt) * 16 + r];

            // S^T*log2e + bias = K·Q' + C ; p = exp2(.)
            unsigned pk0[4], pk1[4];
            #pragma unroll
            for (int t = 0; t < 4; ++t) {
                f32x4 z = mfma32(kf[t][0], qf[qt][0], cin[t]);
                z = mfma32(kf[t][1], qf[qt][1], z);
                float p0 = exp2f(z[0]), p1 = exp2f(z[1]);
                float p2 = exp2f(z[2]), p3 = exp2f(z[3]);
                pk0[t] = cvtpk(p0, p1);
                pk1[t] = cvtpk(p2, p3);
            }

            // WAR fence: previous qt's P reads must finish before overwrite
            asm volatile("s_waitcnt lgkmcnt(0)" ::: "memory");
            __builtin_amdgcn_sched_barrier(0);
            #pragma unroll
            for (int t = 0; t < 4; ++t) {
                u32x2 pk;
                pk[0] = pk0[t]; pk[1] = pk1[t];
                *(u32x2*)(Pw + lr * 72 + t * 16 + lg * 4) = pk;   // P[q=lr][kv]
            }
            __builtin_amdgcn_sched_barrier(0);

            // B-frags: P[kv = w*32+lg*8+e][q = lr]
            bf16x8 pb0 = *(const bf16x8*)(Pw + lr * 72 + lg * 8);
            bf16x8 pb1 = *(const bf16x8*)(Pw + lr * 72 + 32 + lg * 8);

            // lsum via ones-row MFMA (colsum of P)
            lacc[qt] = mfma32(ones, pb0, lacc[qt]);
            lacc[qt] = mfma32(ones, pb1, lacc[qt]);

            // O^T += V^T · P
            #pragma unroll
            for (int dt = 0; dt < 4; ++dt) {
                acc[qt][dt] = mfma32(vf[dt][0], pb0, acc[qt][dt]);
                acc[qt][dt] = mfma32(vf[dt][1], pb1, acc[qt][dt]);
            }
        }
        kp += 64 * 64;
        vp += 64;
        bp += 64;
    }

    // protect P buffers before overlaying Opart
    __builtin_amdgcn_sched_barrier(0);
    __syncthreads();
    __builtin_amdgcn_sched_barrier(0);

    // ---- single-pass split-merge epilogue (every address written once) ----
    float* Opart = (float*)smem;               // [4 sp][4 qt][16 q][68]
    float* Lpart = (float*)(smem + 69632);     // [4 sp][4 qt][16 q]
    #pragma unroll
    for (int qt = 0; qt < 4; ++qt) {
        #pragma unroll
        for (int dt = 0; dt < 4; ++dt)
            *(f32x4*)&Opart[((sp * 4 + qt) * 16 + lr) * 68 + dt * 16 + lg * 4] = acc[qt][dt];
        if (lg == 0) Lpart[(sp * 4 + qt) * 16 + lr] = lacc[qt][0];
    }
    __builtin_amdgcn_sched_barrier(0);
    __syncthreads();
    __builtin_amdgcn_sched_barrier(0);
    {
        const int qi = tid >> 2, quad = tid & 3;      // qi: q row 0..63; quad: 16-d slice
        const int qt2 = qi >> 4, qr = qi & 15;
        f32x4 s0 = {}, s1 = {}, s2 = {}, s3 = {};
        float lt = 0.f;
        #pragma unroll
        for (int s = 0; s < 4; ++s) {
            const float* o = &Opart[((s * 4 + qt2) * 16 + qr) * 68 + quad * 16];
            s0 += *(const f32x4*)(o + 0);
            s1 += *(const f32x4*)(o + 4);
            s2 += *(const f32x4*)(o + 8);
            s3 += *(const f32x4*)(o + 12);
            lt += Lpart[(s * 4 + qt2) * 16 + qr];
        }
        float inv = 1.0f / lt;
        bf16x8 o0, o1;
        o0[0] = f2bf(s0[0] * inv); o0[1] = f2bf(s0[1] * inv);
        o0[2] = f2bf(s0[2] * inv); o0[3] = f2bf(s0[3] * inv);
        o0[4] = f2bf(s1[0] * inv); o0[5] = f2bf(s1[1] * inv);
        o0[6] = f2bf(s1[2] * inv); o0[7] = f2bf(s1[3] * inv);
        o1[0] = f2bf(s2[0] * inv); o1[1] = f2bf(s2[1] * inv);
        o1[2] = f2bf(s2[2] * inv); o1[3] = f2bf(s2[3] * inv);
        o1[4] = f2bf(s3[0] * inv); o1[5] = f2bf(s3[1] * inv);
        o1[6] = f2bf(s3[2] * inv); o1[7] = f2bf(s3[3] * inv);
        short* dst = AO + (size_t)(qb + qi) * 512 + h * 64 + quad * 16;
        *(bf16x8*)(dst) = o0;
        *(bf16x8*)(dst + 8) = o1;
    }
}

// ---------------- launch ----------------
extern "C" void kernel_launch(void* const* d_in, const int* in_sizes, int n_in,
                              void* d_out, int out_size, void* d_ws, size_t ws_size,
                              hipStream_t stream) {
    const float* x   = (const float*)d_in[0];
    const float* pos = (const float*)d_in[1];
    const float* rel = (const float*)d_in[2];
    const float* Wq  = (const float*)d_in[3];
    const float* bq  = (const float*)d_in[4];
    const float* Wk  = (const float*)d_in[5];
    const float* bk  = (const float*)d_in[6];
    const float* Wv  = (const float*)d_in[7];
    const float* bv  = (const float*)d_in[8];
    const float* Wo  = (const float*)d_in[9];
    const float* bo  = (const float*)d_in[10];
    float* out = (float*)d_out;

    char* ws = (char*)d_ws;
    short* xp    = (short*)ws;  ws += (size_t)4096 * 512 * 2;   // reused as VT after gemm0
    short* WqkvT = (short*)ws;  ws += (size_t)1536 * 512 * 2;
    short* WoT   = (short*)ws;  ws += (size_t)512 * 512 * 2;
    short* Qg    = (short*)ws;  ws += (size_t)8 * 4096 * 64 * 2;
    short* Kg    = (short*)ws;  ws += (size_t)8 * 4096 * 64 * 2;
    short* Vg    = (short*)ws;  ws += (size_t)8 * 4096 * 64 * 2;
    short* AO    = (short*)ws;  ws += (size_t)4096 * 512 * 2;
    float* rel2  = (float*)ws;  ws += (size_t)8 * 8192 * 4;
    short* VT    = xp;          // xp is dead after k_gemm<0>

    k_prep_xp<<<dim3(4096 * 512 / (256 * 8)), 256, 0, stream>>>(x, pos, xp);
    k_prep_wqkv<<<dim3(1536 * 512 / 256), 256, 0, stream>>>(Wq, Wk, Wv, WqkvT);
    k_prep_wo<<<dim3(512 * 512 / 256), 256, 0, stream>>>(Wo, WoT);
    k_prep_rel2<<<dim3(8 * 8192 / 256), 256, 0, stream>>>(rel, rel2);

    k_gemm<0><<<dim3(12, 32), 256, 0, stream>>>(xp, WqkvT, bq, bk, bv, Qg, Kg, Vg, nullptr);
    k_vt<<<dim3(64, 8), 256, 0, stream>>>(Vg, VT);
    k_attn3<<<dim3(512), 256, 0, stream>>>(Qg, Kg, VT, rel2, AO);
    k_gemm<1><<<dim3(4, 32), 256, 0, stream>>>(AO, WoT, bo, nullptr, nullptr,
                                               nullptr, nullptr, nullptr, out);
}